// Round 21
// baseline (254.184 us; speedup 1.0000x reference)
//
#include <hip/hip_runtime.h>
#include <hip/hip_fp16.h>

struct alignas(8) half4v { __half2 a, b; };  // 4 halves, 8B
using f16x8 = __attribute__((ext_vector_type(8))) _Float16;  // 4 VGPRs
using f32x4 = __attribute__((ext_vector_type(4))) float;

// ---------------- prep: zero deg + pack W + x->fp16, one range-dispatched launch ----------
__global__ void prep_kernel(int* __restrict__ deg, int n, int nb,
                            const float* __restrict__ x, __half* __restrict__ xh, int total4,
                            const float* __restrict__ W1, __half* __restrict__ Wp1,
                            const float* __restrict__ W2, __half* __restrict__ Wp2,
                            const float* __restrict__ W3, __half* __restrict__ Wp3,
                            const float* __restrict__ W4, __half* __restrict__ Wp4) {
  int b = blockIdx.x;
  if (b < nb) {
    int i = b * 256 + threadIdx.x;
    if (i < n) deg[i] = 0;
  } else if (b < nb + 224) {
    int pb = b - nb;
    const float* W; __half* Wp; int idx;
    if (pb < 32)       { W = W1; Wp = Wp1; idx = pb * 256 + threadIdx.x; }
    else if (pb < 96)  { W = W2; Wp = Wp2; idx = (pb - 32) * 256 + threadIdx.x; }
    else if (pb < 160) { W = W3; Wp = Wp3; idx = (pb - 96) * 256 + threadIdx.x; }
    else               { W = W4; Wp = Wp4; idx = (pb - 160) * 256 + threadIdx.x; }
    int j = idx & 7;
    int lane = (idx >> 3) & 63;
    int c = (idx >> 9) & 7;
    int ks = idx >> 12;
    int k = ks * 32 + ((lane >> 4) << 3) + j;
    int col = c * 16 + (lane & 15);
    Wp[idx] = __float2half(W[k * 128 + col]);
  } else {
    int i = (b - nb - 224) * 256 + threadIdx.x;
    if (i >= total4) return;
    float4 v = ((const float4*)x)[i];
    half4v o;
    o.a = __floats2half2_rn(v.x, v.y);
    o.b = __floats2half2_rn(v.z, v.w);
    ((half4v*)xh)[i] = o;
  }
}

// ---------------- CSR build ----------------
__global__ void hist_kernel(const int* __restrict__ dst, int* __restrict__ deg,
                            int* __restrict__ eidx, int E) {
  int e0 = (blockIdx.x * blockDim.x + threadIdx.x) * 4;
  if (e0 + 3 < E) {
    int4 d4 = *(const int4*)&dst[e0];
    int r0 = atomicAdd(&deg[d4.x], 1);
    int r1 = atomicAdd(&deg[d4.y], 1);
    int r2 = atomicAdd(&deg[d4.z], 1);
    int r3 = atomicAdd(&deg[d4.w], 1);
    int4 o; o.x = r0; o.y = r1; o.z = r2; o.w = r3;
    *(int4*)&eidx[e0] = o;
  } else {
    for (int e = e0; e < E; ++e) eidx[e] = atomicAdd(&deg[dst[e]], 1);
  }
}

__global__ void dinv_bsum_kernel(const int* __restrict__ deg, float* __restrict__ dinv,
                                 int* __restrict__ bsum, int n) {
  __shared__ int s[256];
  int i = blockIdx.x * 256 + threadIdx.x;
  int d = (i < n) ? deg[i] : 0;
  if (i < n) dinv[i] = rsqrtf((float)(d + 1));  // +1 self loop
  s[threadIdx.x] = d;
  __syncthreads();
  for (int off = 128; off > 0; off >>= 1) {
    if (threadIdx.x < off) s[threadIdx.x] += s[threadIdx.x + off];
    __syncthreads();
  }
  if (threadIdx.x == 0) bsum[blockIdx.x] = s[0];
}

__global__ void scan_bsum_kernel(const int* __restrict__ bsum, int* __restrict__ bexcl,
                                 int nb, int* __restrict__ rowptr_last) {
  __shared__ int s[256];
  int t = threadIdx.x;
  int v = (t < nb) ? bsum[t] : 0;
  s[t] = v;
  __syncthreads();
  for (int off = 1; off < 256; off <<= 1) {
    int add = (t >= off) ? s[t - off] : 0;
    __syncthreads();
    s[t] += add;
    __syncthreads();
  }
  if (t < nb) bexcl[t] = s[t] - v;
  if (t == 255) *rowptr_last = s[255];
}

__global__ void rowptr_kernel(const int* __restrict__ cnt, const int* __restrict__ bexcl,
                              int* __restrict__ rowptr, int n) {
  __shared__ int s[256];
  int i = blockIdx.x * 256 + threadIdx.x;
  int t = threadIdx.x;
  int v = (i < n) ? cnt[i] : 0;
  s[t] = v;
  __syncthreads();
  for (int off = 1; off < 256; off <<= 1) {
    int add = (t >= off) ? s[t - off] : 0;
    __syncthreads();
    s[t] += add;
    __syncthreads();
  }
  if (i < n) rowptr[i] = bexcl[blockIdx.x] + s[t] - v;
}

__global__ void fill_kernel(const int* __restrict__ src, const int* __restrict__ dst,
                            const float* __restrict__ dinv, const int* __restrict__ rowptr,
                            const int* __restrict__ eidx, int2* __restrict__ colwv, int E) {
  int e0 = (blockIdx.x * blockDim.x + threadIdx.x) * 2;
  if (e0 + 1 < E) {
    int2 s2 = *(const int2*)&src[e0];
    int2 d2 = *(const int2*)&dst[e0];
    int2 x2 = *(const int2*)&eidx[e0];
    float dsx = dinv[s2.x], ddx = dinv[d2.x];
    float dsy = dinv[s2.y], ddy = dinv[d2.y];
    int slot0 = rowptr[d2.x] + x2.x;
    int slot1 = rowptr[d2.y] + x2.y;
    int2 p0; p0.x = s2.x; p0.y = __float_as_int(dsx * ddx);
    int2 p1; p1.x = s2.y; p1.y = __float_as_int(dsy * ddy);
    colwv[slot0] = p0;
    colwv[slot1] = p1;
  } else if (e0 < E) {
    int s = src[e0], d = dst[e0];
    int slot = rowptr[d] + eidx[e0];
    int2 packed;
    packed.x = s;
    packed.y = __float_as_int(dinv[s] * dinv[d]);
    colwv[slot] = packed;
  }
}

// ---------------- fused aggregate + MFMA GEMM, 8 nodes/block, 4 waves ----------------
// Round-20 lesson: 512-thread blocks retire coarsely (occupancy 49%). Now 256-thread
// blocks, 2 nodes/wave (same short chains), 6250 blocks -> finer backfill + better
// max-of-4 imbalance (1.18x vs 1.25x). Phase 2: 16-row MFMA with rows 8-15 zero
// (row-local, D rows 0-7 exact); each wave 2 col-tiles; stores guarded to rows 0-7.
template <int K>
__global__ __launch_bounds__(256) void agg_gemm_kernel(
    const __half* __restrict__ h, const int* __restrict__ rowptr,
    const int2* __restrict__ colwv, const float* __restrict__ dinv,
    const __half* __restrict__ Wp, const float* __restrict__ bias,
    __half* __restrict__ C, int n) {
  constexpr int RQ = K / 4;        // half4v per row
  constexpr int ROWH = K + 8;      // padded halves per LDS row (16B-aligned)
  __shared__ __half Ash[8 * ROWH];
  const int wave = threadIdx.x >> 6;   // 0..3
  const int lane = threadIdx.x & 63;
  const int n0 = blockIdx.x * 8;
  constexpr int EPG = (K == 128) ? 2 : 4;
  const int sub = (K == 128) ? (lane >> 5) : (lane >> 4);
  const int lq = (K == 128) ? (lane & 31) : (lane & 15);
  const half4v* h4 = (const half4v*)h;
  // ---- phase 1: aggregate 2 nodes per wave ----
  #pragma unroll
  for (int i = 0; i < 2; ++i) {
    int node = n0 + wave * 2 + i;
    if (node < n) {
      float di = dinv[node];
      float sl = di * di;
      int beg = rowptr[node], end = rowptr[node + 1];
      float4 acc = {0.f, 0.f, 0.f, 0.f};
      for (int base = beg; base < end; base += 64) {
        int kk = base + lane;
        int c = 0; float ww = 0.f;  // tail lanes: weight 0 -> row-0 load harmless
        if (kk < end) { int2 e = colwv[kk]; c = e.x; ww = __int_as_float(e.y); }
        int m = end - base; if (m > 64) m = 64;
        for (int t0 = 0; t0 < m; t0 += 8 * EPG) {
          half4v v[8]; float ws[8];
          #pragma unroll
          for (int u = 0; u < 8; ++u) {
            int t = t0 + EPG * u + sub;
            int cs = __shfl(c, t);
            ws[u] = __shfl(ww, t);
            v[u] = h4[(size_t)cs * RQ + lq];
          }
          #pragma unroll
          for (int u = 0; u < 8; ++u) {
            float2 fa = __half22float2(v[u].a);
            float2 fb = __half22float2(v[u].b);
            acc.x += ws[u] * fa.x; acc.y += ws[u] * fa.y;
            acc.z += ws[u] * fb.x; acc.w += ws[u] * fb.y;
          }
        }
      }
      if constexpr (K == 64) {
        acc.x += __shfl_xor(acc.x, 16); acc.y += __shfl_xor(acc.y, 16);
        acc.z += __shfl_xor(acc.z, 16); acc.w += __shfl_xor(acc.w, 16);
      }
      acc.x += __shfl_xor(acc.x, 32); acc.y += __shfl_xor(acc.y, 32);
      acc.z += __shfl_xor(acc.z, 32); acc.w += __shfl_xor(acc.w, 32);
      if (lane < RQ) {
        half4v hv = h4[(size_t)node * RQ + lane];
        float2 fa = __half22float2(hv.a);
        float2 fb = __half22float2(hv.b);
        acc.x += sl * fa.x; acc.y += sl * fa.y; acc.z += sl * fb.x; acc.w += sl * fb.y;
        half4v o;
        o.a = __floats2half2_rn(acc.x, acc.y);
        o.b = __floats2half2_rn(acc.z, acc.w);
        *(half4v*)&Ash[(wave * 2 + i) * ROWH + lane * 4] = o;
      }
    } else if (lane < RQ) {
      half4v z; z.a = __floats2half2_rn(0.f, 0.f); z.b = z.a;
      *(half4v*)&Ash[(wave * 2 + i) * ROWH + lane * 4] = z;
    }
  }
  __syncthreads();
  // ---- phase 2: 16x128 MFMA (rows 8-15 zero), wave w -> cols [32w, 32w+32) ----
  const int lrow = lane & 15;
  const int kgrp = lane >> 4;
  f32x4 acc2[2] = {};
  const f16x8* Wp8 = (const f16x8*)Wp;
  #pragma unroll
  for (int ks = 0; ks < K / 32; ++ks) {
    f16x8 afrag = {};
    if (lrow < 8) afrag = *(const f16x8*)&Ash[lrow * ROWH + ks * 32 + kgrp * 8];
    #pragma unroll
    for (int cc = 0; cc < 2; ++cc) {
      int c = wave * 2 + cc;
      f16x8 bfrag = Wp8[(ks * 8 + c) * 64 + lane];
      acc2[cc] = __builtin_amdgcn_mfma_f32_16x16x32_f16(afrag, bfrag, acc2[cc], 0, 0, 0);
    }
  }
  #pragma unroll
  for (int cc = 0; cc < 2; ++cc) {
    int col = (wave * 2 + cc) * 16 + lrow;
    float bv = bias[col];
    #pragma unroll
    for (int j = 0; j < 4; ++j) {
      int rt = kgrp * 4 + j;      // row in tile (0..15); only 0..7 valid
      int row = n0 + rt;
      if (rt < 8 && row < n) C[(size_t)row * 128 + col] = __float2half(fmaxf(acc2[cc][j] + bv, 0.f));
    }
  }
}

// ---------------- fused pool (segmented mean) + MLP head ----------------
__global__ __launch_bounds__(256) void pool_mlp_kernel(
    const __half* __restrict__ h, const int* __restrict__ batch,
    const float* __restrict__ lW1, const float* __restrict__ lb1,
    const float* __restrict__ lW2, const float* __restrict__ lb2,
    const float* __restrict__ gamma, const float* __restrict__ beta,
    const float* __restrict__ rm, const float* __restrict__ rv,
    const float* __restrict__ oW, const float* __restrict__ ob,
    float* __restrict__ out, int n, int B) {
  int b = blockIdx.x;
  int lo = 0, hi = n;
  while (lo < hi) { int mid = (lo + hi) >> 1; if (batch[mid] < b) lo = mid + 1; else hi = mid; }
  int s = lo;
  hi = n;
  while (lo < hi) { int mid = (lo + hi) >> 1; if (batch[mid] < b + 1) lo = mid + 1; else hi = mid; }
  int e = lo;
  const half4v* h4 = (const half4v*)h;
  int q = threadIdx.x & 31;
  int r = threadIdx.x >> 5;
  float4 acc = {0.f, 0.f, 0.f, 0.f};
  for (int i = s + r; i < e; i += 8) {
    half4v v = h4[(size_t)i * 32 + q];
    float2 fa = __half22float2(v.a), fb = __half22float2(v.b);
    acc.x += fa.x; acc.y += fa.y; acc.z += fb.x; acc.w += fb.y;
  }
  __shared__ float4 red[8][32];
  red[r][q] = acc;
  __syncthreads();
  for (int off = 4; off > 0; off >>= 1) {
    if (r < off) {
      float4 o = red[r + off][q];
      acc.x += o.x; acc.y += o.y; acc.z += o.z; acc.w += o.w;
      red[r][q] = acc;
    }
    __syncthreads();
  }
  __shared__ float p[128], h1[128];
  if (r == 0) {
    float c = fmaxf((float)(e - s), 1.0f);
    float4 o;
    o.x = acc.x / c; o.y = acc.y / c; o.z = acc.z / c; o.w = acc.w / c;
    *(float4*)&p[q * 4] = o;
  }
  __syncthreads();
  int t = threadIdx.x;
  if (t < 128) {
    float a1 = lb1[t];
    for (int k = 0; k < 128; ++k) a1 += p[k] * lW1[k * 128 + t];
    h1[t] = a1;
  }
  __syncthreads();
  if (t < 64) {
    float a2 = lb2[t];
    for (int k = 0; k < 128; ++k) a2 += h1[k] * lW2[k * 64 + t];
    a2 = (a2 - rm[t]) * gamma[t] * rsqrtf(rv[t] + 1e-5f) + beta[t];
    float hd = fmaxf(a2, 0.f);
    out[B + b * 64 + t] = hd;  // hidden, output 1
    float prod = hd * oW[t];
    #pragma unroll
    for (int off = 32; off > 0; off >>= 1) prod += __shfl_down(prod, off);
    if (t == 0) out[b] = prod + ob[0];  // out, output 0
  }
}

extern "C" void kernel_launch(void* const* d_in, const int* in_sizes, int n_in,
                              void* d_out, int out_size, void* d_ws, size_t ws_size,
                              hipStream_t stream) {
  const float* x = (const float*)d_in[0];
  const int* ei = (const int*)d_in[1];
  const int* batch = (const int*)d_in[2];
  const float* W1 = (const float*)d_in[3];  const float* b1 = (const float*)d_in[4];
  const float* W2 = (const float*)d_in[5];  const float* b2 = (const float*)d_in[6];
  const float* W3 = (const float*)d_in[7];  const float* b3 = (const float*)d_in[8];
  const float* W4 = (const float*)d_in[9];  const float* b4 = (const float*)d_in[10];
  const float* lW1 = (const float*)d_in[11]; const float* lb1 = (const float*)d_in[12];
  const float* lW2 = (const float*)d_in[13]; const float* lb2 = (const float*)d_in[14];
  const float* gamma = (const float*)d_in[15]; const float* beta = (const float*)d_in[16];
  const float* rm = (const float*)d_in[17]; const float* rv = (const float*)d_in[18];
  const float* oW = (const float*)d_in[19]; const float* ob = (const float*)d_in[20];

  const int n = in_sizes[2];
  const int E = in_sizes[1] / 2;
  const int B = out_size / 65;  // out_size = B + B*64
  const int* src = ei;
  const int* dst = ei + E;

  char* ws = (char*)d_ws;
  size_t off = 0;
  auto alloc = [&](size_t bytes) -> void* {
    void* p = ws + off;
    off += (bytes + 255) & ~(size_t)255;
    return p;
  };
  int* deg = (int*)alloc((size_t)n * 4);
  float* dinv = (float*)alloc((size_t)n * 4);
  int* rowptr = (int*)alloc((size_t)(n + 1) * 4);
  int* eidx = (int*)alloc((size_t)E * 4);
  int* bsum = (int*)alloc(256 * 4);
  int* bexcl = (int*)alloc(256 * 4);
  int2* colwv = (int2*)alloc((size_t)E * 8);
  __half* hbuf = (__half*)alloc((size_t)n * 128 * 2);
  __half* hbuf2 = (__half*)alloc((size_t)n * 128 * 2);
  __half* xh = (__half*)alloc((size_t)n * 64 * 2);
  __half* Wp1 = (__half*)alloc(64 * 128 * 2);
  __half* Wp2 = (__half*)alloc(128 * 128 * 2);
  __half* Wp3 = (__half*)alloc(128 * 128 * 2);
  __half* Wp4 = (__half*)alloc(128 * 128 * 2);

  const int nb = (n + 255) / 256;  // 196 blocks <= 256, fits single-block scan
  const int f2h_blocks = (n * 16 + 255) / 256;
  prep_kernel<<<nb + 224 + f2h_blocks, 256, 0, stream>>>(deg, n, nb, x, xh, n * 16,
                                                         W1, Wp1, W2, Wp2, W3, Wp3, W4, Wp4);
  hist_kernel<<<(E / 4 + 255) / 256, 256, 0, stream>>>(dst, deg, eidx, E);
  dinv_bsum_kernel<<<nb, 256, 0, stream>>>(deg, dinv, bsum, n);
  scan_bsum_kernel<<<1, 256, 0, stream>>>(bsum, bexcl, nb, rowptr + n);
  rowptr_kernel<<<nb, 256, 0, stream>>>(deg, bexcl, rowptr, n);
  fill_kernel<<<(E / 2 + 255) / 256, 256, 0, stream>>>(src, dst, dinv, rowptr, eidx, colwv, E);

  const int fusedblocks = (n + 7) / 8;  // 8 nodes per block, 4 waves
  agg_gemm_kernel<64><<<fusedblocks, 256, 0, stream>>>(xh, rowptr, colwv, dinv, Wp1, b1, hbuf, n);
  agg_gemm_kernel<128><<<fusedblocks, 256, 0, stream>>>(hbuf, rowptr, colwv, dinv, Wp2, b2, hbuf2, n);
  agg_gemm_kernel<128><<<fusedblocks, 256, 0, stream>>>(hbuf2, rowptr, colwv, dinv, Wp3, b3, hbuf, n);
  agg_gemm_kernel<128><<<fusedblocks, 256, 0, stream>>>(hbuf, rowptr, colwv, dinv, Wp4, b4, hbuf2, n);

  pool_mlp_kernel<<<B, 256, 0, stream>>>(hbuf2, batch, lW1, lb1, lW2, lb2, gamma, beta,
                                         rm, rv, oW, ob, (float*)d_out, n, B);
}

// Round 22
// 236.070 us; speedup vs baseline: 1.0767x; 1.0767x over previous
//
#include <hip/hip_runtime.h>
#include <hip/hip_fp16.h>

struct alignas(8) half4v { __half2 a, b; };  // 4 halves, 8B
using f16x8 = __attribute__((ext_vector_type(8))) _Float16;  // 4 VGPRs
using f32x4 = __attribute__((ext_vector_type(4))) float;

// ---------------- prep: zero deg + pack W + x->fp16, one range-dispatched launch ----------
__global__ void prep_kernel(int* __restrict__ deg, int n, int nb,
                            const float* __restrict__ x, __half* __restrict__ xh, int total4,
                            const float* __restrict__ W1, __half* __restrict__ Wp1,
                            const float* __restrict__ W2, __half* __restrict__ Wp2,
                            const float* __restrict__ W3, __half* __restrict__ Wp3,
                            const float* __restrict__ W4, __half* __restrict__ Wp4) {
  int b = blockIdx.x;
  if (b < nb) {
    int i = b * 256 + threadIdx.x;
    if (i < n) deg[i] = 0;
  } else if (b < nb + 224) {
    int pb = b - nb;
    const float* W; __half* Wp; int idx;
    if (pb < 32)       { W = W1; Wp = Wp1; idx = pb * 256 + threadIdx.x; }
    else if (pb < 96)  { W = W2; Wp = Wp2; idx = (pb - 32) * 256 + threadIdx.x; }
    else if (pb < 160) { W = W3; Wp = Wp3; idx = (pb - 96) * 256 + threadIdx.x; }
    else               { W = W4; Wp = Wp4; idx = (pb - 160) * 256 + threadIdx.x; }
    int j = idx & 7;
    int lane = (idx >> 3) & 63;
    int c = (idx >> 9) & 7;
    int ks = idx >> 12;
    int k = ks * 32 + ((lane >> 4) << 3) + j;
    int col = c * 16 + (lane & 15);
    Wp[idx] = __float2half(W[k * 128 + col]);
  } else {
    int i = (b - nb - 224) * 256 + threadIdx.x;
    if (i >= total4) return;
    float4 v = ((const float4*)x)[i];
    half4v o;
    o.a = __floats2half2_rn(v.x, v.y);
    o.b = __floats2half2_rn(v.z, v.w);
    ((half4v*)xh)[i] = o;
  }
}

// ---------------- CSR build ----------------
__global__ void hist_kernel(const int* __restrict__ dst, int* __restrict__ deg,
                            int* __restrict__ eidx, int E) {
  int e0 = (blockIdx.x * blockDim.x + threadIdx.x) * 4;
  if (e0 + 3 < E) {
    int4 d4 = *(const int4*)&dst[e0];
    int r0 = atomicAdd(&deg[d4.x], 1);
    int r1 = atomicAdd(&deg[d4.y], 1);
    int r2 = atomicAdd(&deg[d4.z], 1);
    int r3 = atomicAdd(&deg[d4.w], 1);
    int4 o; o.x = r0; o.y = r1; o.z = r2; o.w = r3;
    *(int4*)&eidx[e0] = o;
  } else {
    for (int e = e0; e < E; ++e) eidx[e] = atomicAdd(&deg[dst[e]], 1);
  }
}

__global__ void dinv_bsum_kernel(const int* __restrict__ deg, float* __restrict__ dinv,
                                 int* __restrict__ bsum, int n) {
  __shared__ int s[256];
  int i = blockIdx.x * 256 + threadIdx.x;
  int d = (i < n) ? deg[i] : 0;
  if (i < n) dinv[i] = rsqrtf((float)(d + 1));  // +1 self loop
  s[threadIdx.x] = d;
  __syncthreads();
  for (int off = 128; off > 0; off >>= 1) {
    if (threadIdx.x < off) s[threadIdx.x] += s[threadIdx.x + off];
    __syncthreads();
  }
  if (threadIdx.x == 0) bsum[blockIdx.x] = s[0];
}

__global__ void scan_bsum_kernel(const int* __restrict__ bsum, int* __restrict__ bexcl,
                                 int nb, int* __restrict__ rowptr_last) {
  __shared__ int s[256];
  int t = threadIdx.x;
  int v = (t < nb) ? bsum[t] : 0;
  s[t] = v;
  __syncthreads();
  for (int off = 1; off < 256; off <<= 1) {
    int add = (t >= off) ? s[t - off] : 0;
    __syncthreads();
    s[t] += add;
    __syncthreads();
  }
  if (t < nb) bexcl[t] = s[t] - v;
  if (t == 255) *rowptr_last = s[255];
}

__global__ void rowptr_kernel(const int* __restrict__ cnt, const int* __restrict__ bexcl,
                              int* __restrict__ rowptr, int n) {
  __shared__ int s[256];
  int i = blockIdx.x * 256 + threadIdx.x;
  int t = threadIdx.x;
  int v = (i < n) ? cnt[i] : 0;
  s[t] = v;
  __syncthreads();
  for (int off = 1; off < 256; off <<= 1) {
    int add = (t >= off) ? s[t - off] : 0;
    __syncthreads();
    s[t] += add;
    __syncthreads();
  }
  if (i < n) rowptr[i] = bexcl[blockIdx.x] + s[t] - v;
}

__global__ void fill_kernel(const int* __restrict__ src, const int* __restrict__ dst,
                            const float* __restrict__ dinv, const int* __restrict__ rowptr,
                            const int* __restrict__ eidx, int2* __restrict__ colwv, int E) {
  int e0 = (blockIdx.x * blockDim.x + threadIdx.x) * 2;
  if (e0 + 1 < E) {
    int2 s2 = *(const int2*)&src[e0];
    int2 d2 = *(const int2*)&dst[e0];
    int2 x2 = *(const int2*)&eidx[e0];
    float dsx = dinv[s2.x], ddx = dinv[d2.x];
    float dsy = dinv[s2.y], ddy = dinv[d2.y];
    int slot0 = rowptr[d2.x] + x2.x;
    int slot1 = rowptr[d2.y] + x2.y;
    int2 p0; p0.x = s2.x; p0.y = __float_as_int(dsx * ddx);
    int2 p1; p1.x = s2.y; p1.y = __float_as_int(dsy * ddy);
    colwv[slot0] = p0;
    colwv[slot1] = p1;
  } else if (e0 < E) {
    int s = src[e0], d = dst[e0];
    int slot = rowptr[d] + eidx[e0];
    int2 packed;
    packed.x = s;
    packed.y = __float_as_int(dinv[s] * dinv[d]);
    colwv[slot] = packed;
  }
}

// ---------------- fused aggregate + MFMA GEMM, 16 nodes/block, 8 waves ----------------
// Measured optimum of this family (round 20: 236.7us). Round-19 (4 waves, 16 nodes): 45us
// kernel; round-21 (4 waves, 8 nodes): 47.5us -- per-block Wp re-stream + half-wasted MFMA
// dominate. 8 waves x 2 nodes: short serial chains + 1 full col-tile per wave.
template <int K>
__global__ __launch_bounds__(512) void agg_gemm_kernel(
    const __half* __restrict__ h, const int* __restrict__ rowptr,
    const int2* __restrict__ colwv, const float* __restrict__ dinv,
    const __half* __restrict__ Wp, const float* __restrict__ bias,
    __half* __restrict__ C, int n) {
  constexpr int RQ = K / 4;        // half4v per row
  constexpr int ROWH = K + 8;      // padded halves per LDS row (16B-aligned)
  __shared__ __half Ash[16 * ROWH];
  const int wave = threadIdx.x >> 6;   // 0..7
  const int lane = threadIdx.x & 63;
  const int n0 = blockIdx.x * 16;
  constexpr int EPG = (K == 128) ? 2 : 4;
  const int sub = (K == 128) ? (lane >> 5) : (lane >> 4);
  const int lq = (K == 128) ? (lane & 31) : (lane & 15);
  const half4v* h4 = (const half4v*)h;
  // ---- phase 1: aggregate 2 nodes per wave ----
  #pragma unroll
  for (int i = 0; i < 2; ++i) {
    int node = n0 + wave * 2 + i;
    if (node < n) {
      float di = dinv[node];
      float sl = di * di;
      int beg = rowptr[node], end = rowptr[node + 1];
      float4 acc = {0.f, 0.f, 0.f, 0.f};
      for (int base = beg; base < end; base += 64) {
        int kk = base + lane;
        int c = 0; float ww = 0.f;  // tail lanes: weight 0 -> row-0 load harmless
        if (kk < end) { int2 e = colwv[kk]; c = e.x; ww = __int_as_float(e.y); }
        int m = end - base; if (m > 64) m = 64;
        for (int t0 = 0; t0 < m; t0 += 8 * EPG) {
          half4v v[8]; float ws[8];
          #pragma unroll
          for (int u = 0; u < 8; ++u) {
            int t = t0 + EPG * u + sub;
            int cs = __shfl(c, t);
            ws[u] = __shfl(ww, t);
            v[u] = h4[(size_t)cs * RQ + lq];
          }
          #pragma unroll
          for (int u = 0; u < 8; ++u) {
            float2 fa = __half22float2(v[u].a);
            float2 fb = __half22float2(v[u].b);
            acc.x += ws[u] * fa.x; acc.y += ws[u] * fa.y;
            acc.z += ws[u] * fb.x; acc.w += ws[u] * fb.y;
          }
        }
      }
      if constexpr (K == 64) {
        acc.x += __shfl_xor(acc.x, 16); acc.y += __shfl_xor(acc.y, 16);
        acc.z += __shfl_xor(acc.z, 16); acc.w += __shfl_xor(acc.w, 16);
      }
      acc.x += __shfl_xor(acc.x, 32); acc.y += __shfl_xor(acc.y, 32);
      acc.z += __shfl_xor(acc.z, 32); acc.w += __shfl_xor(acc.w, 32);
      if (lane < RQ) {
        half4v hv = h4[(size_t)node * RQ + lane];
        float2 fa = __half22float2(hv.a);
        float2 fb = __half22float2(hv.b);
        acc.x += sl * fa.x; acc.y += sl * fa.y; acc.z += sl * fb.x; acc.w += sl * fb.y;
        half4v o;
        o.a = __floats2half2_rn(acc.x, acc.y);
        o.b = __floats2half2_rn(acc.z, acc.w);
        *(half4v*)&Ash[(wave * 2 + i) * ROWH + lane * 4] = o;
      }
    } else if (lane < RQ) {
      half4v z; z.a = __floats2half2_rn(0.f, 0.f); z.b = z.a;
      *(half4v*)&Ash[(wave * 2 + i) * ROWH + lane * 4] = z;
    }
  }
  __syncthreads();
  // ---- phase 2: 16x128 MFMA, wave w -> cols [16w, 16w+16) ----
  const int lrow = lane & 15;
  const int kgrp = lane >> 4;
  f32x4 acc2 = {};
  const f16x8* Wp8 = (const f16x8*)Wp;
  #pragma unroll
  for (int ks = 0; ks < K / 32; ++ks) {
    f16x8 afrag = *(const f16x8*)&Ash[lrow * ROWH + ks * 32 + kgrp * 8];
    f16x8 bfrag = Wp8[(ks * 8 + wave) * 64 + lane];
    acc2 = __builtin_amdgcn_mfma_f32_16x16x32_f16(afrag, bfrag, acc2, 0, 0, 0);
  }
  const int col = wave * 16 + lrow;
  float bv = bias[col];
  #pragma unroll
  for (int j = 0; j < 4; ++j) {
    int row = n0 + kgrp * 4 + j;
    if (row < n) C[(size_t)row * 128 + col] = __float2half(fmaxf(acc2[j] + bv, 0.f));
  }
}

// ---------------- fused pool (segmented mean) + MLP head ----------------
__global__ __launch_bounds__(256) void pool_mlp_kernel(
    const __half* __restrict__ h, const int* __restrict__ batch,
    const float* __restrict__ lW1, const float* __restrict__ lb1,
    const float* __restrict__ lW2, const float* __restrict__ lb2,
    const float* __restrict__ gamma, const float* __restrict__ beta,
    const float* __restrict__ rm, const float* __restrict__ rv,
    const float* __restrict__ oW, const float* __restrict__ ob,
    float* __restrict__ out, int n, int B) {
  int b = blockIdx.x;
  int lo = 0, hi = n;
  while (lo < hi) { int mid = (lo + hi) >> 1; if (batch[mid] < b) lo = mid + 1; else hi = mid; }
  int s = lo;
  hi = n;
  while (lo < hi) { int mid = (lo + hi) >> 1; if (batch[mid] < b + 1) lo = mid + 1; else hi = mid; }
  int e = lo;
  const half4v* h4 = (const half4v*)h;
  int q = threadIdx.x & 31;
  int r = threadIdx.x >> 5;
  float4 acc = {0.f, 0.f, 0.f, 0.f};
  for (int i = s + r; i < e; i += 8) {
    half4v v = h4[(size_t)i * 32 + q];
    float2 fa = __half22float2(v.a), fb = __half22float2(v.b);
    acc.x += fa.x; acc.y += fa.y; acc.z += fb.x; acc.w += fb.y;
  }
  __shared__ float4 red[8][32];
  red[r][q] = acc;
  __syncthreads();
  for (int off = 4; off > 0; off >>= 1) {
    if (r < off) {
      float4 o = red[r + off][q];
      acc.x += o.x; acc.y += o.y; acc.z += o.z; acc.w += o.w;
      red[r][q] = acc;
    }
    __syncthreads();
  }
  __shared__ float p[128], h1[128];
  if (r == 0) {
    float c = fmaxf((float)(e - s), 1.0f);
    float4 o;
    o.x = acc.x / c; o.y = acc.y / c; o.z = acc.z / c; o.w = acc.w / c;
    *(float4*)&p[q * 4] = o;
  }
  __syncthreads();
  int t = threadIdx.x;
  if (t < 128) {
    float a1 = lb1[t];
    for (int k = 0; k < 128; ++k) a1 += p[k] * lW1[k * 128 + t];
    h1[t] = a1;
  }
  __syncthreads();
  if (t < 64) {
    float a2 = lb2[t];
    for (int k = 0; k < 128; ++k) a2 += h1[k] * lW2[k * 64 + t];
    a2 = (a2 - rm[t]) * gamma[t] * rsqrtf(rv[t] + 1e-5f) + beta[t];
    float hd = fmaxf(a2, 0.f);
    out[B + b * 64 + t] = hd;  // hidden, output 1
    float prod = hd * oW[t];
    #pragma unroll
    for (int off = 32; off > 0; off >>= 1) prod += __shfl_down(prod, off);
    if (t == 0) out[b] = prod + ob[0];  // out, output 0
  }
}

extern "C" void kernel_launch(void* const* d_in, const int* in_sizes, int n_in,
                              void* d_out, int out_size, void* d_ws, size_t ws_size,
                              hipStream_t stream) {
  const float* x = (const float*)d_in[0];
  const int* ei = (const int*)d_in[1];
  const int* batch = (const int*)d_in[2];
  const float* W1 = (const float*)d_in[3];  const float* b1 = (const float*)d_in[4];
  const float* W2 = (const float*)d_in[5];  const float* b2 = (const float*)d_in[6];
  const float* W3 = (const float*)d_in[7];  const float* b3 = (const float*)d_in[8];
  const float* W4 = (const float*)d_in[9];  const float* b4 = (const float*)d_in[10];
  const float* lW1 = (const float*)d_in[11]; const float* lb1 = (const float*)d_in[12];
  const float* lW2 = (const float*)d_in[13]; const float* lb2 = (const float*)d_in[14];
  const float* gamma = (const float*)d_in[15]; const float* beta = (const float*)d_in[16];
  const float* rm = (const float*)d_in[17]; const float* rv = (const float*)d_in[18];
  const float* oW = (const float*)d_in[19]; const float* ob = (const float*)d_in[20];

  const int n = in_sizes[2];
  const int E = in_sizes[1] / 2;
  const int B = out_size / 65;  // out_size = B + B*64
  const int* src = ei;
  const int* dst = ei + E;

  char* ws = (char*)d_ws;
  size_t off = 0;
  auto alloc = [&](size_t bytes) -> void* {
    void* p = ws + off;
    off += (bytes + 255) & ~(size_t)255;
    return p;
  };
  int* deg = (int*)alloc((size_t)n * 4);
  float* dinv = (float*)alloc((size_t)n * 4);
  int* rowptr = (int*)alloc((size_t)(n + 1) * 4);
  int* eidx = (int*)alloc((size_t)E * 4);
  int* bsum = (int*)alloc(256 * 4);
  int* bexcl = (int*)alloc(256 * 4);
  int2* colwv = (int2*)alloc((size_t)E * 8);
  __half* hbuf = (__half*)alloc((size_t)n * 128 * 2);
  __half* hbuf2 = (__half*)alloc((size_t)n * 128 * 2);
  __half* xh = (__half*)alloc((size_t)n * 64 * 2);
  __half* Wp1 = (__half*)alloc(64 * 128 * 2);
  __half* Wp2 = (__half*)alloc(128 * 128 * 2);
  __half* Wp3 = (__half*)alloc(128 * 128 * 2);
  __half* Wp4 = (__half*)alloc(128 * 128 * 2);

  const int nb = (n + 255) / 256;  // 196 blocks <= 256, fits single-block scan
  const int f2h_blocks = (n * 16 + 255) / 256;
  prep_kernel<<<nb + 224 + f2h_blocks, 256, 0, stream>>>(deg, n, nb, x, xh, n * 16,
                                                         W1, Wp1, W2, Wp2, W3, Wp3, W4, Wp4);
  hist_kernel<<<(E / 4 + 255) / 256, 256, 0, stream>>>(dst, deg, eidx, E);
  dinv_bsum_kernel<<<nb, 256, 0, stream>>>(deg, dinv, bsum, n);
  scan_bsum_kernel<<<1, 256, 0, stream>>>(bsum, bexcl, nb, rowptr + n);
  rowptr_kernel<<<nb, 256, 0, stream>>>(deg, bexcl, rowptr, n);
  fill_kernel<<<(E / 2 + 255) / 256, 256, 0, stream>>>(src, dst, dinv, rowptr, eidx, colwv, E);

  const int fusedblocks = (n + 15) / 16;  // 16 nodes per block, 8 waves
  agg_gemm_kernel<64><<<fusedblocks, 512, 0, stream>>>(xh, rowptr, colwv, dinv, Wp1, b1, hbuf, n);
  agg_gemm_kernel<128><<<fusedblocks, 512, 0, stream>>>(hbuf, rowptr, colwv, dinv, Wp2, b2, hbuf2, n);
  agg_gemm_kernel<128><<<fusedblocks, 512, 0, stream>>>(hbuf2, rowptr, colwv, dinv, Wp3, b3, hbuf, n);
  agg_gemm_kernel<128><<<fusedblocks, 512, 0, stream>>>(hbuf, rowptr, colwv, dinv, Wp4, b4, hbuf2, n);

  pool_mlp_kernel<<<B, 256, 0, stream>>>(hbuf2, batch, lW1, lb1, lW2, lb2, gamma, beta,
                                         rm, rv, oW, ob, (float*)d_out, n, B);
}